// Round 1
// baseline (424.278 us; speedup 1.0000x reference)
//
#include <hip/hip_runtime.h>

// 4096-point FWHT per row, one block per row.
// Decomposition: 4096 = 16*16*16. Three in-register 16-pt FWHTs over element
// index bits [3:0], [7:4], [11:8], with two LDS transposes in between.
// All LDS access patterns are <=2 lanes/bank per wave instruction (free).

__device__ __forceinline__ void fwht16(float v[16]) {
#pragma unroll
    for (int s = 1; s < 16; s <<= 1) {
#pragma unroll
        for (int i = 0; i < 16; ++i) {
            if ((i & s) == 0) {
                float a = v[i];
                float b = v[i | s];
                v[i]     = a + b;
                v[i | s] = a - b;
            }
        }
    }
}

__global__ __launch_bounds__(256) void fwht4096_kernel(const float* __restrict__ x,
                                                       float* __restrict__ out) {
    // layout 1 pad: addr1(e) = e + (e>>4)  -> max 17*255+15 = 4350
    // layout 2 pad: addr2(e) = e + 16*(e>>8) -> max 255+272*15 = 4335
    __shared__ float lds[4352];

    const int t = threadIdx.x;            // 0..255
    const size_t base = (size_t)blockIdx.x * 4096;

    float v[16];

    // ---- Load: thread t holds e = 16t + j (j = reg index = e[3:0]) ----
    const float4* px4 = (const float4*)(x + base);
#pragma unroll
    for (int k = 0; k < 4; ++k) {
        float4 q = px4[t * 4 + k];
        v[4 * k + 0] = q.x;
        v[4 * k + 1] = q.y;
        v[4 * k + 2] = q.z;
        v[4 * k + 3] = q.w;
    }

    // ---- Phase 1: bits 0..3 (element strides 1,2,4,8) ----
    fwht16(v);

    // ---- Transpose 1: addr1(e) = e + (e>>4). write addr = 17t + j ----
#pragma unroll
    for (int j = 0; j < 16; ++j) lds[17 * t + j] = v[j];
    __syncthreads();

    // read: t_lo = e[3:0], t_hi = e[11:8], j = e[7:4]
    // e = t_lo + 16j + 256*t_hi ; addr1 = t_lo + 17j + 272*t_hi
    {
        const int t_lo = t & 15, t_hi = t >> 4;
        const int b1 = t_lo + 272 * t_hi;
#pragma unroll
        for (int j = 0; j < 16; ++j) v[j] = lds[b1 + 17 * j];
    }

    // ---- Phase 2: bits 4..7 (element strides 16,32,64,128) ----
    fwht16(v);
    __syncthreads();   // all reads of layout-1 done before layout-2 writes

    // ---- Transpose 2: addr2(e) = e + 16*(e>>8) ----
    // write: e = t_lo + 16j + 256*t_hi ; addr2 = t_lo + 16j + 272*t_hi
    {
        const int t_lo = t & 15, t_hi = t >> 4;
        const int b2 = t_lo + 272 * t_hi;
#pragma unroll
        for (int j = 0; j < 16; ++j) lds[b2 + 16 * j] = v[j];
    }
    __syncthreads();

    // read: t = e[7:0], j = e[11:8]; e = t + 256j ; addr2 = t + 272j
#pragma unroll
    for (int j = 0; j < 16; ++j) v[j] = lds[t + 272 * j];

    // ---- Phase 3: bits 8..11 (element strides 256..2048) ----
    fwht16(v);

    // ---- Scale + store: e = t + 256j ; each wave instr covers 256B contiguous ----
    const float scale = 0.015625f;  // 1/sqrt(4096)
    float* po = out + base;
#pragma unroll
    for (int j = 0; j < 16; ++j) po[t + 256 * j] = v[j] * scale;
}

extern "C" void kernel_launch(void* const* d_in, const int* in_sizes, int n_in,
                              void* d_out, int out_size, void* d_ws, size_t ws_size,
                              hipStream_t stream) {
    const float* x = (const float*)d_in[0];
    float* out = (float*)d_out;
    const int rows = in_sizes[0] >> 12;  // elements / 4096
    fwht4096_kernel<<<rows, 256, 0, stream>>>(x, out);
}